// Round 1
// baseline (140.909 us; speedup 1.0000x reference)
//
#include <hip/hip_runtime.h>

// LogicGatedSNN fused kernel for MI355X (gfx950).
//
// Reference (per row o of O=8192, I=8192):
//   w[o,i]      = (syn[o,i] > 50) ? 1 : 0
//   current[o]  = sum_i w[o,i] * x[i]            (x[i] in {0,1} -> exact int)
//   v_mem       = mp[o]*0.9 + current
//   spike       = (v_mem >= thr[o]) ? 1 : 0
//   new_trace   = clip(trace*0.8 + spike*x, 0, 5)
//   new_thr     = clip(thr + (spike-0.1)*0.1, 1, 20)
//   new_mem     = v_mem * (1-spike) * 0.1
//
// Output layout (float32, flat): [spikes O][new_mem O][new_thr O][new_trace O*I]
//
// Memory-bound: 512 MiB read + 256 MiB write -> ~122 us roofline @6.3 TB/s.

constexpr int O_FEAT = 8192;
constexpr int I_FEAT = 8192;
constexpr float STATE_THR = 50.0f;

__global__ __launch_bounds__(256) void snn_fused_kernel(
    const float* __restrict__ x,    // [I] spike_input (0/1)
    const float* __restrict__ syn,  // [O*I] synapse_states
    const float* __restrict__ mp,   // [O] membrane_potential
    const float* __restrict__ thr,  // [O] adaptive_threshold
    const float* __restrict__ tr,   // [O*I] eligibility_trace
    float* __restrict__ out)        // [3*O + O*I]
{
    const int o = blockIdx.x;
    const int t = threadIdx.x;
    const long long rowoff = (long long)o * I_FEAT;

    const float4* __restrict__ x4 = (const float4*)x;
    const float4* __restrict__ s4 = (const float4*)(syn + rowoff);
    const float4* __restrict__ t4 = (const float4*)(tr + rowoff);
    float4* __restrict__ nt4 = (float4*)(out + 3LL * O_FEAT + rowoff);

    // Phase 1: dot(w_row, x). Keep x fragment in registers for phase 2.
    // Row = 2048 float4; thread t takes float4 indices {t, t+256, ..., t+1792}.
    float4 xr[8];
    float sum = 0.0f;
#pragma unroll
    for (int j = 0; j < 8; ++j) {
        const int idx = j * 256 + t;
        const float4 xv = x4[idx];
        const float4 sv = s4[idx];
        xr[j] = xv;
        // x is exactly 0.0 or 1.0, so (s>50)?x:0 == w*x exactly.
        sum += (sv.x > STATE_THR) ? xv.x : 0.0f;
        sum += (sv.y > STATE_THR) ? xv.y : 0.0f;
        sum += (sv.z > STATE_THR) ? xv.z : 0.0f;
        sum += (sv.w > STATE_THR) ? xv.w : 0.0f;
    }

    // Wave64 shuffle reduce, then cross-wave via LDS.
#pragma unroll
    for (int off = 32; off > 0; off >>= 1)
        sum += __shfl_down(sum, off, 64);

    __shared__ float wsum[4];
    __shared__ float sspike;
    const int wave = t >> 6;
    const int lane = t & 63;
    if (lane == 0) wsum[wave] = sum;
    __syncthreads();

    if (t == 0) {
        const float current = ((wsum[0] + wsum[1]) + wsum[2]) + wsum[3];  // exact: integers
        // v_mem = mp*0.9 + current, no fma-contraction (comparison boundary safety)
        const float v_mem = __fadd_rn(__fmul_rn(mp[o], 0.9f), current);
        const float th = thr[o];
        const float s = (v_mem >= th) ? 1.0f : 0.0f;
        out[o] = s;
        out[O_FEAT + o] = __fmul_rn(__fmul_rn(v_mem, 1.0f - s), 0.1f);
        float nth = __fadd_rn(th, __fmul_rn(s - 0.1f, 0.1f));
        nth = fminf(fmaxf(nth, 1.0f), 20.0f);
        out[2 * O_FEAT + o] = nth;
        sspike = s;
    }
    __syncthreads();
    const float s = sspike;

    // Phase 2: new_trace = clip(tr*0.8 + s*x, 0, 5)
#pragma unroll
    for (int j = 0; j < 8; ++j) {
        const int idx = j * 256 + t;
        const float4 tv = t4[idx];
        const float4 xv = xr[j];
        float4 r;
        r.x = fminf(fmaxf(__fadd_rn(__fmul_rn(tv.x, 0.8f), s * xv.x), 0.0f), 5.0f);
        r.y = fminf(fmaxf(__fadd_rn(__fmul_rn(tv.y, 0.8f), s * xv.y), 0.0f), 5.0f);
        r.z = fminf(fmaxf(__fadd_rn(__fmul_rn(tv.z, 0.8f), s * xv.z), 0.0f), 5.0f);
        r.w = fminf(fmaxf(__fadd_rn(__fmul_rn(tv.w, 0.8f), s * xv.w), 0.0f), 5.0f);
        nt4[idx] = r;
    }
}

extern "C" void kernel_launch(void* const* d_in, const int* in_sizes, int n_in,
                              void* d_out, int out_size, void* d_ws, size_t ws_size,
                              hipStream_t stream) {
    const float* x   = (const float*)d_in[0];  // spike_input [I]
    const float* syn = (const float*)d_in[1];  // synapse_states [O*I]
    const float* mp  = (const float*)d_in[2];  // membrane_potential [O]
    const float* th  = (const float*)d_in[3];  // adaptive_threshold [O]
    const float* tr  = (const float*)d_in[4];  // eligibility_trace [O*I]
    float* out = (float*)d_out;

    snn_fused_kernel<<<O_FEAT, 256, 0, stream>>>(x, syn, mp, th, tr, out);
}